// Round 5
// baseline (4488.425 us; speedup 1.0000x reference)
//
#include <hip/hip_runtime.h>

#define NC    64      // channels C
#define NATTR 10      // node attrs
#define KSC   640     // C*NATTR
#define NH    64      // radial MLP hidden
#define NRAD  8       // radial features
#define TE    32      // edges per tile in msg kernel
#define G     8       // receivers per block in msg kernel

__device__ __forceinline__ float silu_f(float x) { return x / (1.0f + __expf(-x)); }

// ---------------------------------------------------------------------------
// d_out layout (f32, out_size = N*512):
//   out_s : [0,       N*64 )
//   out_v : [N*64,    N*256)   (N,C,3) row-major
//   sc_s  : [N*256,   N*320)
//   sc_v  : [N*320,   N*512)   (N,C,3) row-major
// The sc region doubles as scratch for the self-linear s,v until sc_kernel
// (launched last) overwrites it:
//   s at N*256 + n*64 + d            (layout [N][64])
//   v at N*320 + n*192 + x*64 + d    (layout [N][3][64])
// ---------------------------------------------------------------------------

// ---------------- CSR build ----------------
__global__ void hist_kernel(const int* __restrict__ rcv, int* __restrict__ deg, int E)
{
    int e = blockIdx.x * 256 + threadIdx.x;
    if (e < E) atomicAdd(&deg[rcv[e]], 1);
}

__global__ __launch_bounds__(256)
void scan_kernel(const int* __restrict__ deg, int* __restrict__ row_ptr, int N)
{
    __shared__ int sums[256];
    __shared__ int offs[257];
    const int t = threadIdx.x;
    const int chunk = (N + 255) / 256;
    int b = t * chunk, e = min(N, b + chunk);
    int s = 0;
    for (int k = b; k < e; k++) s += deg[k];
    sums[t] = s;
    __syncthreads();
    if (t == 0) {
        int run = 0;
        for (int i = 0; i < 256; i++) { offs[i] = run; run += sums[i]; }
        offs[256] = run;
    }
    __syncthreads();
    int run = offs[t];
    for (int k = b; k < e; k++) { row_ptr[k] = run; run += deg[k]; }
    if (t == 255) row_ptr[N] = offs[256];
}

__global__ void fill_kernel(const int* __restrict__ rcv, const int* __restrict__ row_ptr,
                            int* __restrict__ cursor, int* __restrict__ eidx, int E)
{
    int e = blockIdx.x * 256 + threadIdx.x;
    if (e < E) {
        int r = rcv[e];
        int pos = atomicAdd(&cursor[r], 1);
        eidx[row_ptr[r] + pos] = e;
    }
}

// ---------------- self linear (s,v scratch into d_out sc region) ----------------
__global__ __launch_bounds__(256)
void self_kernel(const float* __restrict__ fs, const float* __restrict__ fv,
                 const float* __restrict__ Wes, const float* __restrict__ Wev,
                 float* __restrict__ out, int N)
{
    __shared__ float s_l[NC];
    __shared__ float v_l[3][NC];
    const int n = blockIdx.x, t = threadIdx.x;

    if (t < NC) s_l[t] = fs[(size_t)n * NC + t];
    for (int i = t; i < NC * 3; i += 256) {
        int c = i / 3, x = i - c * 3;
        v_l[x][c] = fv[(size_t)n * NC * 3 + i];
    }
    __syncthreads();

    const int wave = t >> 6, d = t & 63;
    if (wave == 0) {
        float a = 0.f;
        #pragma unroll 8
        for (int c = 0; c < NC; c++) a += s_l[c] * Wes[c * NC + d];
        out[(size_t)N * 256 + (size_t)n * NC + d] = a * 0.125f;       // 1/sqrt(64)
    } else {
        const int x = wave - 1;
        float a = 0.f;
        #pragma unroll 8
        for (int c = 0; c < NC; c++) a += v_l[x][c] * Wev[c * NC + d];
        out[(size_t)N * 320 + (size_t)n * 192 + x * NC + d] = a * 0.125f;
    }
}

// ---------------------------------------------------------------------------
// Fused message-passing kernel: block owns G=8 consecutive receivers, walks
// their contiguous CSR edge range in TE=32-edge tiles: radial MLP (batched) +
// tensor product -> LDS accumulators (ds_add_f32) -> output linear -> d_out.
// acc per-receiver layout: [0,64) p1 | [64,128) p2 |
//                          128 + x*192 + {0:p3, 64:p4, 128:p5} + c
// ---------------------------------------------------------------------------
__global__ __launch_bounds__(256)
void msg_kernel(const float* __restrict__ ef, const float* __restrict__ sh0,
                const float* __restrict__ sh1,
                const int* __restrict__ snd, const int* __restrict__ rcv,
                const float* __restrict__ W1, const float* __restrict__ W2,
                const float* __restrict__ W3, const float* __restrict__ W4,
                const float* __restrict__ s_st, const float* __restrict__ v_st,
                const int* __restrict__ row_ptr, const int* __restrict__ eidx,
                const float* __restrict__ Wos, const float* __restrict__ Wov,
                float* __restrict__ out, int N)
{
    __shared__ float acc[G][704];
    __shared__ float h_a[TE][NH];
    __shared__ float h_b[TE][NH];
    __shared__ float wp[3][TE][64];
    __shared__ float x_l[TE][NRAD];
    __shared__ float sh0_l[TE];
    __shared__ float sh1_l[TE][3];
    __shared__ int   snd_l[TE];
    __shared__ int   g_l[TE];

    const int t = threadIdx.x;
    const int r0 = blockIdx.x * G;
    const int gc = min(G, N - r0);

    for (int i = t; i < G * 704; i += 256) (&acc[0][0])[i] = 0.f;
    __syncthreads();

    const int ebeg = row_ptr[r0];
    const int eend = row_ptr[r0 + gc];

    for (int ts0 = ebeg; ts0 < eend; ts0 += TE) {
        const int nt = min(TE, eend - ts0);

        if (t < TE) {
            if (t < nt) {
                int e = eidx[ts0 + t];
                snd_l[t] = snd[e];
                g_l[t]   = rcv[e] - r0;
                sh0_l[t] = sh0[e];
                sh1_l[t][0] = sh1[(size_t)e * 3 + 0];
                sh1_l[t][1] = sh1[(size_t)e * 3 + 1];
                sh1_l[t][2] = sh1[(size_t)e * 3 + 2];
                #pragma unroll
                for (int r = 0; r < NRAD; r++) x_l[t][r] = ef[(size_t)e * NRAD + r];
            } else {
                g_l[t] = -1; snd_l[t] = 0; sh0_l[t] = 0.f;
                sh1_l[t][0] = sh1_l[t][1] = sh1_l[t][2] = 0.f;
                #pragma unroll
                for (int r = 0; r < NRAD; r++) x_l[t][r] = 0.f;
            }
        }
        __syncthreads();

        for (int i = t; i < TE * NH; i += 256) {          // layer 1: 8 -> 64
            int e = i >> 6, j = i & 63;
            float a = 0.f;
            #pragma unroll
            for (int r = 0; r < NRAD; r++) a += x_l[e][r] * W1[r * NH + j];
            h_a[e][j] = silu_f(a * 0.35355339059327373f);  // 1/sqrt(8)
        }
        __syncthreads();
        for (int i = t; i < TE * NH; i += 256) {          // layer 2
            int e = i >> 6, j = i & 63;
            float a = 0.f;
            #pragma unroll 8
            for (int c = 0; c < NH; c++) a += h_a[e][c] * W2[c * NH + j];
            h_b[e][j] = silu_f(a * 0.125f);
        }
        __syncthreads();
        for (int i = t; i < TE * NH; i += 256) {          // layer 3
            int e = i >> 6, j = i & 63;
            float a = 0.f;
            #pragma unroll 8
            for (int c = 0; c < NH; c++) a += h_b[e][c] * W3[c * NH + j];
            h_a[e][j] = silu_f(a * 0.125f);
        }
        __syncthreads();

        // ---- pass A: scalar-sender paths p1 (w slice 0), p3 (w slice 128) ----
        for (int sl = 0; sl < 2; sl++) {
            int off = (sl == 0) ? 0 : 128;
            for (int i = t; i < TE * 64; i += 256) {
                int e = i >> 6, j = i & 63;
                float a = 0.f;
                #pragma unroll 8
                for (int c = 0; c < NH; c++) a += h_a[e][c] * W4[c * 320 + off + j];
                wp[sl][e][j] = a * 0.125f;                // 1/sqrt(64)
            }
        }
        __syncthreads();
        for (int i = t; i < TE * 64; i += 256) {
            int e = i >> 6, c = i & 63;
            int g = g_l[e];
            if (g < 0) continue;
            float se = s_st[(size_t)snd_l[e] * NC + c];
            float s0 = sh0_l[e];
            float w1v = wp[0][e][c], w3v = wp[1][e][c];
            atomicAdd(&acc[g][c], w1v * se * s0);                       // p1
            float t3 = w3v * se;                                        // p3
            atomicAdd(&acc[g][128 + 0 * 192 + c], t3 * sh1_l[e][0]);
            atomicAdd(&acc[g][128 + 1 * 192 + c], t3 * sh1_l[e][1]);
            atomicAdd(&acc[g][128 + 2 * 192 + c], t3 * sh1_l[e][2]);
        }
        __syncthreads();

        // ---- pass B: vector-sender paths p2 (slice 64), p4 (192), p5 (256) ----
        {
            const int offB[3] = {64, 192, 256};
            for (int sl = 0; sl < 3; sl++) {
                int off = offB[sl];
                for (int i = t; i < TE * 64; i += 256) {
                    int e = i >> 6, j = i & 63;
                    float a = 0.f;
                    #pragma unroll 8
                    for (int c = 0; c < NH; c++) a += h_a[e][c] * W4[c * 320 + off + j];
                    wp[sl][e][j] = a * 0.125f;
                }
            }
        }
        __syncthreads();
        for (int i = t; i < TE * 64; i += 256) {
            int e = i >> 6, c = i & 63;
            int g = g_l[e];
            if (g < 0) continue;
            size_t sb = (size_t)snd_l[e] * 192;
            float vx = v_st[sb + c];
            float vy = v_st[sb + 64 + c];
            float vz = v_st[sb + 128 + c];
            float shx = sh1_l[e][0], shy = sh1_l[e][1], shz = sh1_l[e][2];
            float s0 = sh0_l[e];
            float w2v = wp[0][e][c], w4v = wp[1][e][c], w5v = wp[2][e][c];

            float dot = vx * shx + vy * shy + vz * shz;
            atomicAdd(&acc[g][64 + c], w2v * dot * 0.5773502691896258f);  // p2
            float w4s = w4v * s0;                                          // p4
            atomicAdd(&acc[g][128 + 0 * 192 + 64 + c], w4s * vx);
            atomicAdd(&acc[g][128 + 1 * 192 + 64 + c], w4s * vy);
            atomicAdd(&acc[g][128 + 2 * 192 + 64 + c], w4s * vz);
            float w5s = w5v * 0.7071067811865476f;                         // p5
            atomicAdd(&acc[g][128 + 0 * 192 + 128 + c], w5s * (vy * shz - vz * shy));
            atomicAdd(&acc[g][128 + 1 * 192 + 128 + c], w5s * (vz * shx - vx * shz));
            atomicAdd(&acc[g][128 + 2 * 192 + 128 + c], w5s * (vx * shy - vy * shx));
        }
        __syncthreads();
    }

    // ---- output linear from LDS accumulators ----
    const int wave = t >> 6, d = t & 63;
    if (wave == 0) {
        float a[G];
        #pragma unroll
        for (int g = 0; g < G; g++) a[g] = 0.f;
        for (int k = 0; k < 128; k++) {
            float wk = Wos[k * 64 + d];
            #pragma unroll
            for (int g = 0; g < G; g++) a[g] += acc[g][k] * wk;
        }
        for (int g = 0; g < gc; g++)
            out[(size_t)(r0 + g) * 64 + d] = a[g] * 0.005524271728019903f;   // 1/(sqrt(128)*16)
    } else {
        const int x = wave - 1;
        float a[G];
        #pragma unroll
        for (int g = 0; g < G; g++) a[g] = 0.f;
        for (int k = 0; k < 192; k++) {
            float wk = Wov[k * 64 + d];
            #pragma unroll
            for (int g = 0; g < G; g++) a[g] += acc[g][128 + x * 192 + k] * wk;
        }
        for (int g = 0; g < gc; g++)
            out[(size_t)N * 64 + (size_t)(r0 + g) * 192 + d * 3 + x] =
                a[g] * 0.004510527174164819f;                                 // 1/(sqrt(192)*16)
    }
}

// ---------------------------------------------------------------------------
// skip connection (runs last; overwrites the s/v scratch region of d_out).
// ---------------------------------------------------------------------------
__global__ __launch_bounds__(256)
void sc_kernel(const float* __restrict__ attrs, const float* __restrict__ fs,
               const float* __restrict__ fv,
               const float* __restrict__ Wss, const float* __restrict__ Wsv,
               float* __restrict__ out, int N)
{
    __shared__ float a_l[NATTR];
    __shared__ float s_l[NC];
    __shared__ float v_l[3][NC];
    __shared__ float ts[KSC];
    __shared__ float tv[3][KSC];

    const int n = blockIdx.x, t = threadIdx.x;

    if (t < NC) s_l[t] = fs[(size_t)n * NC + t];
    if (t >= 64 && t < 64 + NATTR) a_l[t - 64] = attrs[(size_t)n * NATTR + (t - 64)];
    for (int i = t; i < NC * 3; i += 256) {
        int c = i / 3, x = i - c * 3;
        v_l[x][c] = fv[(size_t)n * NC * 3 + i];
    }
    __syncthreads();

    for (int k = t; k < KSC; k += 256) {
        int c = k / NATTR, a = k - c * NATTR;
        float av = a_l[a];
        ts[k]    = s_l[c] * av;
        tv[0][k] = v_l[0][c] * av;
        tv[1][k] = v_l[1][c] * av;
        tv[2][k] = v_l[2][c] * av;
    }
    __syncthreads();

    const int wave = t >> 6, d = t & 63;
    const float inv_sc = 0.03952847075210474f;  // 1/sqrt(640)
    if (wave == 0) {
        float acc = 0.f;
        #pragma unroll 8
        for (int k = 0; k < KSC; k++) acc += ts[k] * Wss[k * NC + d];
        out[(size_t)N * 256 + (size_t)n * NC + d] = acc * inv_sc;
    } else {
        const int x = wave - 1;
        float acc = 0.f;
        #pragma unroll 8
        for (int k = 0; k < KSC; k++) acc += tv[x][k] * Wsv[k * NC + d];
        out[(size_t)N * 320 + (size_t)n * 192 + d * 3 + x] = acc * inv_sc;
    }
}

// ---------------------------------------------------------------------------
extern "C" void kernel_launch(void* const* d_in, const int* in_sizes, int n_in,
                              void* d_out, int out_size, void* d_ws, size_t ws_size,
                              hipStream_t stream)
{
    const float* attrs = (const float*)d_in[0];
    const float* fs    = (const float*)d_in[1];
    const float* fv    = (const float*)d_in[2];
    const float* sh0   = (const float*)d_in[3];
    const float* sh1   = (const float*)d_in[4];
    const float* ef    = (const float*)d_in[5];
    const int*   snd   = (const int*)d_in[6];
    const int*   rcv   = (const int*)d_in[7];
    const float* Wss   = (const float*)d_in[8];
    const float* Wsv   = (const float*)d_in[9];
    const float* Wes   = (const float*)d_in[10];
    const float* Wev   = (const float*)d_in[11];
    const float* W1    = (const float*)d_in[12];
    const float* W2    = (const float*)d_in[13];
    const float* W3    = (const float*)d_in[14];
    const float* W4    = (const float*)d_in[15];
    const float* Wos   = (const float*)d_in[16];
    const float* Wov   = (const float*)d_in[17];

    const int N = in_sizes[0] / NATTR;   // 50000
    const int E = in_sizes[6];           // 320000

    float* out = (float*)d_out;
    const float* s_st = out + (size_t)N * 256;  // self-linear s scratch (in d_out)
    const float* v_st = out + (size_t)N * 320;  // self-linear v scratch (in d_out)

    // ws layout (ints): deg[N] | cursor[N] | row_ptr[N+1] | eidx[E]   (~1.9 MB)
    int* deg     = (int*)d_ws;
    int* cursor  = deg + N;
    int* row_ptr = cursor + N;
    int* eidx    = row_ptr + N + 1;

    hipMemsetAsync(deg, 0, (size_t)2 * N * sizeof(int), stream);

    const int eb = (E + 255) / 256;
    hist_kernel<<<eb, 256, 0, stream>>>(rcv, deg, E);
    scan_kernel<<<1, 256, 0, stream>>>(deg, row_ptr, N);
    fill_kernel<<<eb, 256, 0, stream>>>(rcv, row_ptr, cursor, eidx, E);

    self_kernel<<<N, 256, 0, stream>>>(fs, fv, Wes, Wev, out, N);

    const int nb = (N + G - 1) / G;
    msg_kernel<<<nb, 256, 0, stream>>>(ef, sh0, sh1, snd, rcv,
                                       W1, W2, W3, W4, s_st, v_st,
                                       row_ptr, eidx, Wos, Wov, out, N);

    sc_kernel<<<N, 256, 0, stream>>>(attrs, fs, fv, Wss, Wsv, out, N);
}

// Round 6
// 2123.577 us; speedup vs baseline: 2.1136x; 2.1136x over previous
//
#include <hip/hip_runtime.h>

#define NC    64      // channels C
#define NATTR 10      // node attrs
#define NH    64      // radial MLP hidden
#define NRAD  8       // radial features
#define TEB   128     // CSR positions per edge block
#define MPN   704     // f32 message floats per node

__device__ __forceinline__ float silu_f(float x) { return x / (1.0f + __expf(-x)); }

// ---------------------------------------------------------------------------
// d_out layout (f32, out_size = N*512):
//   out_s : [0,      N*64 )   -- also CSR int scratch until out written
//   out_v : [N*64,   N*256)
//   sc_s  : [N*256,  N*320)   -- self-linear s scratch until sc_kernel
//   sc_v  : [N*320,  N*512)   -- self-linear v scratch until sc_kernel
// ws: m[N*704] f32 message accumulator (140.8 MB)
// ---------------------------------------------------------------------------

// ---------------- CSR build (scratch ints live in d_out's out region) ------
__global__ void hist_kernel(const int* __restrict__ rcv, int* __restrict__ deg, int E)
{
    int e = blockIdx.x * 256 + threadIdx.x;
    if (e < E) atomicAdd(&deg[rcv[e]], 1);
}

__global__ __launch_bounds__(256)
void scan_kernel(const int* __restrict__ deg, int* __restrict__ row_ptr, int N)
{
    __shared__ int sums[256];
    __shared__ int offs[257];
    const int t = threadIdx.x;
    const int chunk = (N + 255) / 256;
    int b = t * chunk, e = min(N, b + chunk);
    int s = 0;
    for (int k = b; k < e; k++) s += deg[k];
    sums[t] = s;
    __syncthreads();
    if (t == 0) {
        int run = 0;
        for (int i = 0; i < 256; i++) { offs[i] = run; run += sums[i]; }
        offs[256] = run;
    }
    __syncthreads();
    int run = offs[t];
    for (int k = b; k < e; k++) { row_ptr[k] = run; run += deg[k]; }
    if (t == 255) row_ptr[N] = offs[256];
}

__global__ void fill_kernel(const int* __restrict__ rcv, const int* __restrict__ row_ptr,
                            int* __restrict__ cursor, int* __restrict__ eidx, int E)
{
    int e = blockIdx.x * 256 + threadIdx.x;
    if (e < E) {
        int r = rcv[e];
        int pos = atomicAdd(&cursor[r], 1);
        eidx[row_ptr[r] + pos] = e;
    }
}

// ---------------- self linear (s,v scratch into d_out sc region) -----------
__global__ __launch_bounds__(256)
void self_kernel(const float* __restrict__ fs, const float* __restrict__ fv,
                 const float* __restrict__ Wes, const float* __restrict__ Wev,
                 float* __restrict__ out, int N)
{
    __shared__ float s_l[NC];
    __shared__ float v_l[3][NC];
    const int n = blockIdx.x, t = threadIdx.x;

    if (t < NC) s_l[t] = fs[(size_t)n * NC + t];
    for (int i = t; i < NC * 3; i += 256) {
        int c = i / 3, x = i - c * 3;
        v_l[x][c] = fv[(size_t)n * NC * 3 + i];
    }
    __syncthreads();

    const int wave = t >> 6, d = t & 63;
    if (wave == 0) {
        float a = 0.f;
        #pragma unroll 8
        for (int c = 0; c < NC; c++) a += s_l[c] * Wes[c * NC + d];
        out[(size_t)N * 256 + (size_t)n * NC + d] = a * 0.125f;
    } else {
        const int x = wave - 1;
        float a = 0.f;
        #pragma unroll 8
        for (int c = 0; c < NC; c++) a += v_l[x][c] * Wev[c * NC + d];
        out[(size_t)N * 320 + (size_t)n * 192 + x * NC + d] = a * 0.125f;
    }
}

// ---------------------------------------------------------------------------
// Edge kernel: 128 CSR positions per 128-thread block.
// Phase 1: thread-per-edge radial MLP layers 1-3 (weights via uniform/scalar
//          loads, activations in registers; h3 -> LDS row).
// Phase 2: wave-per-edge layer 4 (W4 column slice in 64 VGPRs, reused across
//          edges) + tensor product + coalesced atomics into m (CSR-ordered
//          edges -> receiver-local atomic lines stay hot in L2).
// m per-node layout: [0,64) p1 | [64,128) p2 | 128 + x*192 + {0:p3,64:p4,128:p5}
// ---------------------------------------------------------------------------
__global__ __launch_bounds__(128)
void edge_kernel(const float* __restrict__ ef, const float* __restrict__ sh0,
                 const float* __restrict__ sh1,
                 const int* __restrict__ snd, const int* __restrict__ rcv,
                 const float* __restrict__ W1, const float* __restrict__ W2,
                 const float* __restrict__ W3, const float* __restrict__ W4,
                 const float* __restrict__ s_st, const float* __restrict__ v_st,
                 const int* __restrict__ eidx,
                 float* __restrict__ m, int E)
{
    __shared__ float h_l[TEB][68];     // h3 rows (pad 68 for aligned b128)
    __shared__ float sh1_l[TEB][3];
    __shared__ float sh0_l[TEB];
    __shared__ int   snd_l[TEB];
    __shared__ int   rcv_l[TEB];

    const int t = threadIdx.x;
    const int p0 = blockIdx.x * TEB;

    // ---------------- phase 1 ----------------
    {
        int p = p0 + t;
        bool valid = p < E;
        int e = valid ? eidx[p] : 0;
        snd_l[t] = valid ? snd[e] : 0;
        rcv_l[t] = valid ? rcv[e] : -1;
        sh0_l[t] = valid ? sh0[e] : 0.f;
        sh1_l[t][0] = valid ? sh1[(size_t)e * 3 + 0] : 0.f;
        sh1_l[t][1] = valid ? sh1[(size_t)e * 3 + 1] : 0.f;
        sh1_l[t][2] = valid ? sh1[(size_t)e * 3 + 2] : 0.f;

        float x[NRAD];
        #pragma unroll
        for (int r = 0; r < NRAD; r++)
            x[r] = valid ? ef[(size_t)e * NRAD + r] : 0.f;

        // layer 1: 8 -> 64 (h1 in registers)
        float h1[NH];
        #pragma unroll
        for (int j = 0; j < NH; j++) {
            float a = 0.f;
            #pragma unroll
            for (int r = 0; r < NRAD; r++) a += x[r] * W1[r * NH + j];
            h1[j] = silu_f(a * 0.35355339059327373f);   // 1/sqrt(8)
        }

        // layer 2: h1(regs) -> h2 (LDS row), j tiled by 4
        for (int jt = 0; jt < 16; jt++) {
            float a0 = 0.f, a1 = 0.f, a2 = 0.f, a3 = 0.f;
            #pragma unroll
            for (int c = 0; c < NH; c++) {
                float hv = h1[c];
                const float* wr = W2 + c * NH + jt * 4;
                a0 += hv * wr[0]; a1 += hv * wr[1];
                a2 += hv * wr[2]; a3 += hv * wr[3];
            }
            h_l[t][jt * 4 + 0] = silu_f(a0 * 0.125f);
            h_l[t][jt * 4 + 1] = silu_f(a1 * 0.125f);
            h_l[t][jt * 4 + 2] = silu_f(a2 * 0.125f);
            h_l[t][jt * 4 + 3] = silu_f(a3 * 0.125f);
        }
        // copy h2 back to registers (own row; same-thread LDS RAW is ordered
        // by compiler-inserted lgkmcnt)
        float h2[NH];
        #pragma unroll
        for (int c = 0; c < NH; c++) h2[c] = h_l[t][c];
        // layer 3: h2(regs) -> h3 (LDS row, overwrites h2)
        for (int jt = 0; jt < 16; jt++) {
            float a0 = 0.f, a1 = 0.f, a2 = 0.f, a3 = 0.f;
            #pragma unroll
            for (int c = 0; c < NH; c++) {
                float hv = h2[c];
                const float* wr = W3 + c * NH + jt * 4;
                a0 += hv * wr[0]; a1 += hv * wr[1];
                a2 += hv * wr[2]; a3 += hv * wr[3];
            }
            h_l[t][jt * 4 + 0] = silu_f(a0 * 0.125f);
            h_l[t][jt * 4 + 1] = silu_f(a1 * 0.125f);
            h_l[t][jt * 4 + 2] = silu_f(a2 * 0.125f);
            h_l[t][jt * 4 + 3] = silu_f(a3 * 0.125f);
        }
    }
    __syncthreads();

    // ---------------- phase 2 ----------------
    const int wv = t >> 6, lane = t & 63;
    const int base_pos = wv * 64;

    for (int s = 0; s < 5; s++) {
        // W4 column slice for this lane, reused across all 64 edges
        float W4c[NH];
        #pragma unroll
        for (int c = 0; c < NH; c++) W4c[c] = W4[c * 320 + s * 64 + lane];

        for (int ei = 0; ei < 64; ei++) {
            int pos = base_pos + ei;
            int r = rcv_l[pos];
            if (r < 0) continue;                         // uniform (tail only)
            int sd = __builtin_amdgcn_readfirstlane(snd_l[pos]);

            // issue gathers early (overlap with the 64-FMA w-compute)
            float se = 0.f, vx = 0.f, vy = 0.f, vz = 0.f;
            if (s == 0 || s == 2) {
                se = s_st[(size_t)sd * NC + lane];
            } else {
                size_t sb = (size_t)sd * 192;
                vx = v_st[sb + lane];
                vy = v_st[sb + 64 + lane];
                vz = v_st[sb + 128 + lane];
            }

            float a0 = 0.f, a1 = 0.f, a2 = 0.f, a3 = 0.f;
            #pragma unroll
            for (int c = 0; c < NH; c += 4) {
                a0 += h_l[pos][c]     * W4c[c];
                a1 += h_l[pos][c + 1] * W4c[c + 1];
                a2 += h_l[pos][c + 2] * W4c[c + 2];
                a3 += h_l[pos][c + 3] * W4c[c + 3];
            }
            float w = (a0 + a1 + a2 + a3) * 0.125f;      // 1/sqrt(64)
            float s0  = sh0_l[pos];
            float shx = sh1_l[pos][0], shy = sh1_l[pos][1], shz = sh1_l[pos][2];
            float* mb = m + (size_t)r * MPN;

            if (s == 0) {
                unsafeAtomicAdd(mb + lane, w * se * s0);                         // p1
            } else if (s == 1) {
                float dot = vx * shx + vy * shy + vz * shz;
                unsafeAtomicAdd(mb + 64 + lane, w * dot * 0.5773502691896258f);  // p2
            } else if (s == 2) {
                float t3 = w * se;                                               // p3
                unsafeAtomicAdd(mb + 128 + lane,       t3 * shx);
                unsafeAtomicAdd(mb + 128 + 192 + lane, t3 * shy);
                unsafeAtomicAdd(mb + 128 + 384 + lane, t3 * shz);
            } else if (s == 3) {
                float w4s = w * s0;                                              // p4
                unsafeAtomicAdd(mb + 128 + 64 + lane,       w4s * vx);
                unsafeAtomicAdd(mb + 128 + 192 + 64 + lane, w4s * vy);
                unsafeAtomicAdd(mb + 128 + 384 + 64 + lane, w4s * vz);
            } else {
                float w5s = w * 0.7071067811865476f;                             // p5
                unsafeAtomicAdd(mb + 128 + 128 + lane,       w5s * (vy * shz - vz * shy));
                unsafeAtomicAdd(mb + 128 + 192 + 128 + lane, w5s * (vz * shx - vx * shz));
                unsafeAtomicAdd(mb + 128 + 384 + 128 + lane, w5s * (vx * shy - vy * shx));
            }
        }
    }
}

// ---------------------------------------------------------------------------
// Skip-connection as tiled GEMM: C[64n x 64d] per block, A[n][k]=feat*attr
// built on the fly, B-tile staged, 4x4 register blocking. blockIdx.y = part
// (0: scalar->sc_s, 1..3: vector x -> sc_v).
// ---------------------------------------------------------------------------
__global__ __launch_bounds__(256)
void sc_kernel(const float* __restrict__ attrs, const float* __restrict__ fs,
               const float* __restrict__ fv,
               const float* __restrict__ Wss, const float* __restrict__ Wsv,
               float* __restrict__ out, int N)
{
    __shared__ float At[64][68];   // [kk][n]
    __shared__ float Bt[64][68];   // [kk][d]

    const int part = blockIdx.y;
    const int n0 = blockIdx.x * 64;
    const int t = threadIdx.x;
    const int tn = t & 15, td = t >> 4;
    const float* W = (part == 0) ? Wss : Wsv;
    const int x = part - 1;

    float acc[4][4];
    #pragma unroll
    for (int i = 0; i < 4; i++)
        #pragma unroll
        for (int j = 0; j < 4; j++) acc[i][j] = 0.f;

    for (int kt = 0; kt < 10; kt++) {
        __syncthreads();
        // build A-tile
        for (int i = t; i < 4096; i += 256) {
            int kk = i >> 6, n = i & 63;
            int k = kt * 64 + kk;
            int c = k / 10, am = k - c * 10;
            int ng = n0 + n;
            float v = 0.f;
            if (ng < N) {
                float f = (part == 0) ? fs[(size_t)ng * 64 + c]
                                      : fv[((size_t)ng * 64 + c) * 3 + x];
                v = f * attrs[(size_t)ng * 10 + am];
            }
            At[kk][n] = v;
        }
        // load B-tile
        for (int i = t; i < 4096; i += 256) {
            int kk = i >> 6, d = i & 63;
            Bt[kk][d] = W[(size_t)(kt * 64 + kk) * 64 + d];
        }
        __syncthreads();
        #pragma unroll 8
        for (int kk = 0; kk < 64; kk++) {
            float a4[4], b4[4];
            #pragma unroll
            for (int i = 0; i < 4; i++) a4[i] = At[kk][tn * 4 + i];
            #pragma unroll
            for (int j = 0; j < 4; j++) b4[j] = Bt[kk][td * 4 + j];
            #pragma unroll
            for (int i = 0; i < 4; i++)
                #pragma unroll
                for (int j = 0; j < 4; j++) acc[i][j] += a4[i] * b4[j];
        }
    }

    const float inv_sc = 0.03952847075210474f;  // 1/sqrt(640)
    #pragma unroll
    for (int i = 0; i < 4; i++) {
        int ng = n0 + tn * 4 + i;
        if (ng >= N) continue;
        #pragma unroll
        for (int j = 0; j < 4; j++) {
            int d = td * 4 + j;
            float v = acc[i][j] * inv_sc;
            if (part == 0) out[(size_t)N * 256 + (size_t)ng * 64 + d] = v;
            else           out[(size_t)N * 320 + (size_t)ng * 192 + d * 3 + x] = v;
        }
    }
}

// ---------------------------------------------------------------------------
// Output linear as tiled GEMM over m. blockIdx.y = part (0: scalar k=128,
// 1..3: vector x, k=192).
// ---------------------------------------------------------------------------
__global__ __launch_bounds__(256)
void outlin_kernel(const float* __restrict__ m,
                   const float* __restrict__ Wos, const float* __restrict__ Wov,
                   float* __restrict__ out, int N)
{
    __shared__ float At[64][68];
    __shared__ float Bt[64][68];

    const int part = blockIdx.y;
    const int n0 = blockIdx.x * 64;
    const int t = threadIdx.x;
    const int tn = t & 15, td = t >> 4;
    const int x = part - 1;
    const int ntiles = (part == 0) ? 2 : 3;
    const int aoff = (part == 0) ? 0 : 128 + x * 192;
    const float* W = (part == 0) ? Wos : Wov;

    float acc[4][4];
    #pragma unroll
    for (int i = 0; i < 4; i++)
        #pragma unroll
        for (int j = 0; j < 4; j++) acc[i][j] = 0.f;

    for (int kt = 0; kt < ntiles; kt++) {
        __syncthreads();
        for (int i = t; i < 4096; i += 256) {
            int kk = i >> 6, n = i & 63;
            int ng = n0 + n;
            At[kk][n] = (ng < N) ? m[(size_t)ng * MPN + aoff + kt * 64 + kk] : 0.f;
        }
        for (int i = t; i < 4096; i += 256) {
            int kk = i >> 6, d = i & 63;
            Bt[kk][d] = W[(size_t)(kt * 64 + kk) * 64 + d];
        }
        __syncthreads();
        #pragma unroll 8
        for (int kk = 0; kk < 64; kk++) {
            float a4[4], b4[4];
            #pragma unroll
            for (int i = 0; i < 4; i++) a4[i] = At[kk][tn * 4 + i];
            #pragma unroll
            for (int j = 0; j < 4; j++) b4[j] = Bt[kk][td * 4 + j];
            #pragma unroll
            for (int i = 0; i < 4; i++)
                #pragma unroll
                for (int j = 0; j < 4; j++) acc[i][j] += a4[i] * b4[j];
        }
    }

    const float scale = (part == 0) ? 0.005524271728019903f    // 1/(sqrt(128)*16)
                                    : 0.004510527174164819f;   // 1/(sqrt(192)*16)
    #pragma unroll
    for (int i = 0; i < 4; i++) {
        int ng = n0 + tn * 4 + i;
        if (ng >= N) continue;
        #pragma unroll
        for (int j = 0; j < 4; j++) {
            int d = td * 4 + j;
            float v = acc[i][j] * scale;
            if (part == 0) out[(size_t)ng * 64 + d] = v;
            else           out[(size_t)N * 64 + (size_t)ng * 192 + d * 3 + x] = v;
        }
    }
}

// ---------------------------------------------------------------------------
extern "C" void kernel_launch(void* const* d_in, const int* in_sizes, int n_in,
                              void* d_out, int out_size, void* d_ws, size_t ws_size,
                              hipStream_t stream)
{
    const float* attrs = (const float*)d_in[0];
    const float* fs    = (const float*)d_in[1];
    const float* fv    = (const float*)d_in[2];
    const float* sh0   = (const float*)d_in[3];
    const float* sh1   = (const float*)d_in[4];
    const float* ef    = (const float*)d_in[5];
    const int*   snd   = (const int*)d_in[6];
    const int*   rcv   = (const int*)d_in[7];
    const float* Wss   = (const float*)d_in[8];
    const float* Wsv   = (const float*)d_in[9];
    const float* Wes   = (const float*)d_in[10];
    const float* Wev   = (const float*)d_in[11];
    const float* W1    = (const float*)d_in[12];
    const float* W2    = (const float*)d_in[13];
    const float* W3    = (const float*)d_in[14];
    const float* W4    = (const float*)d_in[15];
    const float* Wos   = (const float*)d_in[16];
    const float* Wov   = (const float*)d_in[17];

    const int N = in_sizes[0] / NATTR;   // 50000
    const int E = in_sizes[6];           // 320000

    float* out = (float*)d_out;
    const float* s_st = out + (size_t)N * 256;  // self-linear s scratch
    const float* v_st = out + (size_t)N * 320;  // self-linear v scratch

    // CSR int scratch in d_out's out region (overwritten later by outlin)
    int* deg     = (int*)d_out;
    int* cursor  = deg + N;
    int* row_ptr = cursor + N;
    int* eidx    = row_ptr + N + 1;

    float* m = (float*)d_ws;             // N*704 f32 = 140.8 MB (fits: round-4)

    hipMemsetAsync(deg, 0, (size_t)2 * N * sizeof(int), stream);
    hipMemsetAsync(m, 0, (size_t)N * MPN * sizeof(float), stream);

    const int eb = (E + 255) / 256;
    hist_kernel<<<eb, 256, 0, stream>>>(rcv, deg, E);
    scan_kernel<<<1, 256, 0, stream>>>(deg, row_ptr, N);
    fill_kernel<<<eb, 256, 0, stream>>>(rcv, row_ptr, cursor, eidx, E);

    self_kernel<<<N, 256, 0, stream>>>(fs, fv, Wes, Wev, out, N);

    const int nbe = (E + TEB - 1) / TEB;
    edge_kernel<<<nbe, 128, 0, stream>>>(ef, sh0, sh1, snd, rcv,
                                         W1, W2, W3, W4, s_st, v_st,
                                         eidx, m, E);

    dim3 g_out((N + 63) / 64, 4);
    outlin_kernel<<<g_out, 256, 0, stream>>>(m, Wos, Wov, out, N);

    dim3 g_sc((N + 63) / 64, 4);
    sc_kernel<<<g_sc, 256, 0, stream>>>(attrs, fs, fv, Wss, Wsv, out, N);
}